// Round 4
// baseline (195.272 us; speedup 1.0000x reference)
//
#include <hip/hip_runtime.h>

// SecureOptimizedBlockReLU (16,128,114,114) fp32 — two streaming passes.
// sign = f32_block_sum > -1.0f (trunc/floordiv/shift chain preserves sign class;
// int16 wrap unreachable; row-major sequential sum order — absmax 0.0 R1-R3).
//
// Pass 1: one wg per ch>=32 plane. Contiguous float4 -> LDS, compute block
//         masks, write byte masks to d_ws (3.1 MB, L2/L3-resident for pass 2).
// Pass 2: pure grid-stride float4 copy in->out with inline mask multiply.
//         Structurally identical to the 6.3 TB/s copy pattern — this is the
//         decisive test of the 2.4 TB/s cap seen in R2/R3.

typedef float v4 __attribute__((ext_vector_type(4)));

#define PLANE 12996
#define P4 3249          // float4 per plane (exact: 3249*4 = 12996)
#define WS4_BASE 2495232 // 768 * 3249 bytes of 2x2 masks, then 768*841 of 4x4

// ---- pass 1: masks ----
__global__ __launch_bounds__(256) void mask_kernel(const float* __restrict__ in,
                                                   unsigned char* __restrict__ ws) {
    __shared__ float Lp[PLANE];          // 51984 B -> 3 wg/CU
    const int wg  = blockIdx.x;          // 0..1535
    const int n   = wg / 96;
    const int cr  = wg - n * 96;         // 0..95 -> channel 32+cr
    const int tid = threadIdx.x;
    const v4* __restrict__ ip = (const v4*)(in + (size_t)(n * 128 + 32 + cr) * PLANE);

    // contiguous coalesced stage: 12 full rounds + 177 tail
    v4 r[12];
#pragma unroll
    for (int i = 0; i < 12; ++i) r[i] = ip[tid + 256 * i];
    v4 rt;
    if (tid < 177) rt = ip[tid + 3072];
#pragma unroll
    for (int i = 0; i < 12; ++i) *(v4*)&Lp[4 * (tid + 256 * i)] = r[i];
    if (tid < 177) *(v4*)&Lp[4 * (tid + 3072)] = rt;
    __syncthreads();

    if (cr < 48) {
        // 2x2: 57x57 = 3249 cells
        unsigned char* mp = ws + (size_t)(n * 48 + cr) * 3249;
        for (int b = tid; b < 3249; b += 256) {
            int bh = b / 57, bw = b - bh * 57;
            const float* p = &Lp[228 * bh + 2 * bw];
            float s = ((p[0] + p[1]) + p[114]) + p[115];   // row-major sequential
            mp[b] = (s > -1.0f) ? 1 : 0;
        }
    } else {
        // 4x4: 29x29 = 841 cells (edges 2-wide/2-tall; pad zeros exact no-ops)
        unsigned char* mp = ws + WS4_BASE + (size_t)(n * 48 + (cr - 48)) * 841;
        for (int b = tid; b < 841; b += 256) {
            int bh = b / 29, bw = b - bh * 29;
            int h0 = 4 * bh, w0 = 4 * bw;
            int nh = (bh == 28) ? 2 : 4;
            int nw = (bw == 28) ? 2 : 4;
            float s = 0.0f;
            for (int r2 = 0; r2 < nh; ++r2) {
                const float* p = &Lp[(h0 + r2) * 114 + w0];
                for (int j = 0; j < nw; ++j) s += p[j];    // row-major sequential
            }
            mp[b] = (s > -1.0f) ? 1 : 0;
        }
    }
}

// ---- pass 2: copy + mask apply (grid-stride copy shape) ----
__global__ __launch_bounds__(256) void apply_kernel(const float* __restrict__ in,
                                                    const unsigned char* __restrict__ ws,
                                                    float* __restrict__ out) {
    const int i = blockIdx.x * 256 + threadIdx.x;   // float4 index, exact grid
    v4 v = ((const v4*)in)[i];
    int plane = i / P4;                  // magic-div (const divisor)
    int rr    = i - plane * P4;
    int c     = plane & 127;             // wave-uniform (1KB wave span << 52KB plane)
    v4 o;
    if (c < 32) {
        o = v;
    } else {
        int q = 4 * rr;
        int h = q / 114;
        int w = q - h * 114;
        if (c < 80) {
            const unsigned char* mp = ws + (size_t)((plane >> 7) * 48 + (c - 32)) * 3249;
#pragma unroll
            for (int e = 0; e < 4; ++e) {
                o[e] = v[e] * (float)mp[(h >> 1) * 57 + (w >> 1)];
                if (++w == 114) { w = 0; ++h; }      // float4 may straddle rows
            }
        } else {
            const unsigned char* mp = ws + WS4_BASE + (size_t)((plane >> 7) * 48 + (c - 80)) * 841;
#pragma unroll
            for (int e = 0; e < 4; ++e) {
                o[e] = v[e] * (float)mp[(h >> 2) * 29 + (w >> 2)];
                if (++w == 114) { w = 0; ++h; }
            }
        }
    }
    __builtin_nontemporal_store(o, &((v4*)out)[i]);  // out never re-read
}

extern "C" void kernel_launch(void* const* d_in, const int* in_sizes, int n_in,
                              void* d_out, int out_size, void* d_ws, size_t ws_size,
                              hipStream_t stream) {
    const float* in = (const float*)d_in[0];
    float* out = (float*)d_out;
    unsigned char* ws = (unsigned char*)d_ws;
    mask_kernel<<<1536, 256, 0, stream>>>(in, ws);
    // 16*128*3249 float4 = 6,653,952 = 25992 * 256 exactly
    apply_kernel<<<25992, 256, 0, stream>>>(in, ws, out);
}